// Round 2
// baseline (3556.551 us; speedup 1.0000x reference)
//
#include <hip/hip_runtime.h>

// NetG: seq2seq GRU (enc GRU -> +noise -> dec GRU -> FC head)
// B=512, T=256, H=256, D=3.
//
// R14 = R13 (4-way hidden-split GRU) with the two launch/coherence risks fixed:
//   a) PLAIN launches (no hipLaunchCooperativeKernel): the flag protocol only
//      needs co-residency, and grid=128 blocks <= 256 CUs guarantees it.
//      R13's cooperative launch was almost certainly rejected under the
//      harness's graph capture (error swallowed -> kernels never ran ->
//      nondeterministic garbage absmax 468 / 1.16).
//   b) Exchange payload moved with 64-bit AGENT-scope relaxed atomics
//      (sc1 -> coherence point; immune to per-XCD L2 / L1 staleness no
//      matter where partner blocks land). Fences kept as belt+suspenders.
// Structure (from R13): 128 blocks x 256 thr (4 waves). Block (g,ch) owns
// hidden tiles ch*4..ch*4+3 (64 dims) of batch-group g. Per wave: 1 tile x
// 3 gates -> all A-frags resident (no LDS weights, no in-loop weight loads).
// Per-step h exchange via parity-double-buffered global Hx + per-chunk step
// flags: publish own 512B fragment -> syncthreads (vmcnt drain) -> release
// fence + flag store -> poll partner flags -> acquire fence -> copy 3
// partner chunks (6 KB) into LDS h. Enc uses flag values 1..255, dec +256;
// flags memset once per launch. bid = ch*32+g puts all 4 partners on one
// XCD under wgid%8 dispatch (perf-only, not correctness).
// Frozen from R6..R12: fp32 register h carry (exact), bf16 GEMM operands,
// fragment-order h LDS layout, native v_exp gates, x staged in LDS with the
// decoder shift baked in, interleaved x-step MFMA re-init under the trans
// tail.

#define B_TOT 512
#define T_LEN 256
#define HID 256
#define NBATCH 16
#define NTHREADS 256
#define NGROUP 32
#define NCHUNK 4
#define NBLK (NGROUP * NCHUNK)

#define HBUF (NBATCH * HID)          // 4096 shorts per h parity buffer
#define XT 64
#define XSLOTS (T_LEN + 1)
#define X_OFF (2 * HBUF)             // 8192 shorts
#define SMEM_SHORTS (X_OFF + XSLOTS * XT)   // 8192 + 16448 = 24640
#define SMEM_BYTES  (SMEM_SHORTS * 2)       // 49280 B (< 64 KiB)

typedef __attribute__((ext_vector_type(4))) float f32x4;
typedef __attribute__((ext_vector_type(8))) short shortx8;
typedef __attribute__((ext_vector_type(4))) short i16x4;
typedef __attribute__((ext_vector_type(4))) unsigned short ushortx4;
typedef __attribute__((ext_vector_type(8))) unsigned short ushortx8;

#if __has_builtin(__builtin_amdgcn_mfma_f32_16x16x16_bf16)
#define HAVE_K16 1
#define MFMA_X(A, B, C) __builtin_amdgcn_mfma_f32_16x16x16_bf16((A), (B), (C), 0, 0, 0)
#elif __has_builtin(__builtin_amdgcn_mfma_f32_16x16x16bf16_1k)
#define HAVE_K16 1
#define MFMA_X(A, B, C) __builtin_amdgcn_mfma_f32_16x16x16bf16_1k((A), (B), (C), 0, 0, 0)
#else
#define HAVE_K16 0
#endif

__device__ __forceinline__ unsigned short f2bf(float x) {
    unsigned u = __float_as_uint(x);
    u += 0x7FFF + ((u >> 16) & 1);   // RNE
    return (unsigned short)(u >> 16);
}
__device__ __forceinline__ float bf2f(unsigned short s) {
    return __uint_as_float(((unsigned)s) << 16);
}
__device__ __forceinline__ float fastrcp(float x) {
#if __has_builtin(__builtin_amdgcn_rcpf)
    return __builtin_amdgcn_rcpf(x);
#else
    return 1.0f / x;
#endif
}
__device__ __forceinline__ float exp2raw(float y) {
#if __has_builtin(__builtin_amdgcn_exp2f)
    return __builtin_amdgcn_exp2f(y);
#else
    return __expf(y * 0.69314718056f);
#endif
}
__device__ __forceinline__ float sigmoid_(float x) {
    return fastrcp(1.0f + exp2raw(x * -1.44269504f));
}
__device__ __forceinline__ float tanh_(float x) {
    return 2.0f * fastrcp(1.0f + exp2raw(x * -2.88539008f)) - 1.0f;
}

template<int IS_DEC>
__global__ __launch_bounds__(NTHREADS, 1) void gru_persistent(
    const float* __restrict__ X,       // [512][256][3]
    const float* __restrict__ W_hh,    // [768][256] gates r,z,n
    const float* __restrict__ W_ih,    // [768][3]
    const float* __restrict__ b_ih,    // [768]
    const float* __restrict__ b_hh,    // [768]
    const float* __restrict__ h_in,    // dec: [512][256] fp32; enc: null
    const float* __restrict__ noise,   // dec: [512][256]; enc: null
    float* __restrict__ h_out,         // enc: [512][256] fp32; dec: null
    unsigned short* __restrict__ Yout, // dec: [32][256][16][256] bf16
    unsigned short* __restrict__ Hx,   // [32 groups][2 parity][4096] shorts
    unsigned int* __restrict__ flags)  // [32 groups][4 chunks]
{
    extern __shared__ unsigned short smem[];
    unsigned short* shH = smem;            // 2 parity buffers, fragment order
    unsigned short* shX = smem + X_OFF;

    const int tid  = threadIdx.x;
    const int bid  = blockIdx.x;
    const int ch   = bid >> 5;         // hidden chunk 0..3
    const int g    = bid & 31;         // batch group 0..31 (partners same XCD)
    const int w    = tid >> 6;         // wave 0..3
    const int lane = tid & 63;
    const int c    = lane & 15;
    const int q    = lane >> 4;
    const int ht   = (ch << 2) | w;    // global hidden tile 0..15

    unsigned short* HxG = Hx + (size_t)g * (2 * HBUF);
    unsigned int* flg = flags + g * NCHUNK;
    const unsigned FLAGBASE = IS_DEC ? (unsigned)T_LEN : 0u;

    // ---- stage X into LDS (bf16, shift baked in; slot t = x for step t) ----
    for (int idx = tid; idx < NBATCH * XSLOTS; idx += NTHREADS) {
        int t = idx >> 4, cc = idx & 15;
        int ts = IS_DEC ? (t - 1) : t;
        float x0 = 0.0f, x1 = 0.0f, x2 = 0.0f;
        if (ts >= 0 && ts < T_LEN) {
            const float* xp = X + ((size_t)(g * NBATCH + cc) * T_LEN + ts) * 3;
            x0 = xp[0]; x1 = xp[1]; x2 = xp[2];
        }
        ushortx4 v = {f2bf(x0), f2bf(x1), f2bf(x2), (unsigned short)0x3F80};
        *(ushortx4*)&shX[t * XT + cc * 4] = v;
    }

    // ---- ALL three gates' A-frags resident (1 tile/wave -> 96 VGPRs) ----
    shortx8 Wf[3][8];   // [r|z|n][k]
    #pragma unroll
    for (int gg = 0; gg < 3; ++gg) {
        int row = gg * 256 + ht * 16 + c;
        const float* wp = W_hh + (size_t)row * 256 + q * 8;
        #pragma unroll
        for (int k = 0; k < 8; ++k) {
            const f32x4* p = (const f32x4*)(wp + k * 32);
            f32x4 f0 = p[0];
            f32x4 f1 = p[1];
            shortx8 a;
            a[0] = (short)f2bf(f0[0]); a[1] = (short)f2bf(f0[1]);
            a[2] = (short)f2bf(f0[2]); a[3] = (short)f2bf(f0[3]);
            a[4] = (short)f2bf(f1[0]); a[5] = (short)f2bf(f1[1]);
            a[6] = (short)f2bf(f1[2]); a[7] = (short)f2bf(f1[3]);
            Wf[gg][k] = a;
        }
    }

    // ---- x/bias A-frags (q==0 lanes carry data; others MUST be zero) ----
#if HAVE_K16
    i16x4 ax[3];
#else
    shortx8 ax[3];
#endif
    {
        int rr_ = ht * 16 + c;
        int rowr = rr_, rowz = 256 + rr_, rown = 512 + rr_;
        short r0 = 0, r1 = 0, r2 = 0, r3 = 0, z0 = 0, z1 = 0, z2 = 0, z3 = 0;
        short n0 = 0, n1 = 0, n2 = 0, n3 = 0;
        if (q == 0) {
            r0 = (short)f2bf(W_ih[rowr * 3 + 0]);
            r1 = (short)f2bf(W_ih[rowr * 3 + 1]);
            r2 = (short)f2bf(W_ih[rowr * 3 + 2]);
            r3 = (short)f2bf(b_ih[rowr] + b_hh[rowr]);
            z0 = (short)f2bf(W_ih[rowz * 3 + 0]);
            z1 = (short)f2bf(W_ih[rowz * 3 + 1]);
            z2 = (short)f2bf(W_ih[rowz * 3 + 2]);
            z3 = (short)f2bf(b_ih[rowz] + b_hh[rowz]);
            n0 = (short)f2bf(W_ih[rown * 3 + 0]);
            n1 = (short)f2bf(W_ih[rown * 3 + 1]);
            n2 = (short)f2bf(W_ih[rown * 3 + 2]);
            n3 = (short)f2bf(b_ih[rown]);
        }
#if HAVE_K16
        ax[0] = i16x4{r0, r1, r2, r3};
        ax[1] = i16x4{z0, z1, z2, z3};
        ax[2] = i16x4{n0, n1, n2, n3};
#else
        ax[0] = shortx8{r0, r1, r2, r3, 0, 0, 0, 0};
        ax[1] = shortx8{z0, z1, z2, z3, 0, 0, 0, 0};
        ax[2] = shortx8{n0, n1, n2, n3, 0, 0, 0, 0};
#endif
    }

    // ---- nh-bias register constants (b_hh n-gate, this lane's rows) ----
    f32x4 nhb = *(const f32x4*)(b_hh + 512 + ht * 16 + q * 4);

    // fragment-order offset of this lane's 4 h values within an h buffer:
    // value (batch c, dim ht*16+q*4+r) lives at ht*256 + (q>>1)*128 +
    // (q&1)*4 + c*8 + r  (tile ht = contiguous 512 B -> chunk = 2 KB)
    const int woff = ht * 256 + (q >> 1) * 128 + (q & 1) * 4 + c * 8;

    // ---- init h0: fp32 carry in regs; bf16 full h into parity buffer 0 ----
    f32x4 hold;
    if (IS_DEC) {
        for (int idx = tid; idx < HBUF; idx += NTHREADS) {
            int cc = idx & 15, d = idx >> 4;
            size_t gi = (size_t)(g * NBATCH + cc) * HID + d;
            float v = h_in[gi] + noise[gi];
            int qq = (d >> 2) & 3;
            int off = (d >> 4) * 256 + (qq >> 1) * 128 + (qq & 1) * 4 + cc * 8 + (d & 3);
            shH[off] = f2bf(v);
        }
        int b = g * NBATCH + c;
        const float* hp = h_in + (size_t)b * HID + ht * 16 + q * 4;
        const float* np = noise + (size_t)b * HID + ht * 16 + q * 4;
        #pragma unroll
        for (int r = 0; r < 4; ++r) hold[r] = hp[r] + np[r];
    } else {
        for (int u = tid; u < HBUF / 4; u += NTHREADS)
            *(ushortx4*)(shH + u * 4) = ushortx4{0, 0, 0, 0};
        hold = f32x4{0.0f, 0.0f, 0.0f, 0.0f};
    }

    // ---- incremental decoder Y pointer (step stride = 4096 shorts) ----
    unsigned short* yp = nullptr;
    if (IS_DEC)
        yp = Yout + ((size_t)g * T_LEN * NBATCH + c) * HID + ht * 16 + q * 4;

    __syncthreads();

    const f32x4 zc = {0.0f, 0.0f, 0.0f, 0.0f};

    // ---- x-step for t=0 ----
    f32x4 acc0, acc1, acc2, acc3;   // r, z, nh, nx
    {
#if HAVE_K16
        i16x4 bx = *(const i16x4*)&shX[c * 4];
        acc0 = MFMA_X(ax[0], bx, zc);
        acc1 = MFMA_X(ax[1], bx, zc);
        acc3 = MFMA_X(ax[2], bx, zc);
#else
        ushortx4 xv = *(const ushortx4*)&shX[c * 4];
        shortx8 bx = (q == 0)
            ? shortx8{(short)xv[0], (short)xv[1], (short)xv[2], (short)xv[3], 0, 0, 0, 0}
            : shortx8{0, 0, 0, 0, 0, 0, 0, 0};
        acc0 = __builtin_amdgcn_mfma_f32_16x16x32_bf16(ax[0], bx, zc, 0, 0, 0);
        acc1 = __builtin_amdgcn_mfma_f32_16x16x32_bf16(ax[1], bx, zc, 0, 0, 0);
        acc3 = __builtin_amdgcn_mfma_f32_16x16x32_bf16(ax[2], bx, zc, 0, 0, 0);
#endif
    }

    const int bbase = q * 128 + c * 8;   // lane's B-frag base within a buffer
    int xidx = XT + c * 4;               // x slot for step t+1 (incremental)

    // ---- recurrence ----
    for (int t = 0; t < T_LEN; ++t) {
        const unsigned short* brow = shH + (t & 1) * HBUF + bbase;
        unsigned short* hn = shH + ((t + 1) & 1) * HBUF;
        const int par = (t + 1) & 1;

        acc2 = nhb;
        #pragma unroll
        for (int k = 0; k < 8; ++k) {
            shortx8 bf = *(const shortx8*)(brow + k * 512);
            acc0 = __builtin_amdgcn_mfma_f32_16x16x32_bf16(Wf[0][k], bf, acc0, 0, 0, 0);
            acc1 = __builtin_amdgcn_mfma_f32_16x16x32_bf16(Wf[1][k], bf, acc1, 0, 0, 0);
            acc2 = __builtin_amdgcn_mfma_f32_16x16x32_bf16(Wf[2][k], bf, acc2, 0, 0, 0);
        }

        // bx for step t+1
#if HAVE_K16
        i16x4 bxn = *(const i16x4*)&shX[xidx];
#else
        ushortx4 xvn = *(const ushortx4*)&shX[xidx];
        shortx8 bxn = (q == 0)
            ? shortx8{(short)xvn[0], (short)xvn[1], (short)xvn[2], (short)xvn[3], 0, 0, 0, 0}
            : shortx8{0, 0, 0, 0, 0, 0, 0, 0};
#endif
        xidx += XT;

        // ---- epilogue (1 tile) ----
        f32x4 ho;
        #pragma unroll
        for (int r = 0; r < 4; ++r) {
            float rr = sigmoid_(acc0[r]);
            float zz = sigmoid_(acc1[r]);
            float nn = tanh_(acc3[r] + rr * acc2[r]);
            ho[r] = nn + zz * (hold[r] - nn);
        }
        hold = ho;
        ushortx4 hb16 = {f2bf(ho[0]), f2bf(ho[1]), f2bf(ho[2]), f2bf(ho[3])};
        *(ushortx4*)(hn + woff) = hb16;                  // own tile -> LDS
        // publish to partners: agent-scope (sc1) store -> coherence point,
        // valid regardless of which XCDs the partner blocks landed on
        unsigned long long pub;
        __builtin_memcpy(&pub, &hb16, 8);
        __hip_atomic_store((unsigned long long*)(HxG + par * HBUF + woff), pub,
                           __ATOMIC_RELAXED, __HIP_MEMORY_SCOPE_AGENT);
        if (IS_DEC) {
            __builtin_nontemporal_store(hb16, (ushortx4*)yp);   // keep L2 clean
            yp += NBATCH * HID;
        }

        // x-step re-init for t+1 (independent MFMAs under the trans tail)
#if HAVE_K16
        acc0 = MFMA_X(ax[0], bxn, zc);
        acc1 = MFMA_X(ax[1], bxn, zc);
        acc3 = MFMA_X(ax[2], bxn, zc);
#else
        acc0 = __builtin_amdgcn_mfma_f32_16x16x32_bf16(ax[0], bxn, zc, 0, 0, 0);
        acc1 = __builtin_amdgcn_mfma_f32_16x16x32_bf16(ax[1], bxn, zc, 0, 0, 0);
        acc3 = __builtin_amdgcn_mfma_f32_16x16x32_bf16(ax[2], bxn, zc, 0, 0, 0);
#endif

        if (t == T_LEN - 1) break;   // last h never consumed by a next GEMM

        // ---- inter-block h exchange ----
        __syncthreads();   // all threads' publish stores ack'd (vmcnt drain)
        if (tid == 0) {
            __builtin_amdgcn_fence(__ATOMIC_RELEASE, "agent");
            __hip_atomic_store(&flg[ch], FLAGBASE + (unsigned)(t + 1),
                               __ATOMIC_RELAXED, __HIP_MEMORY_SCOPE_AGENT);
        }
        if (tid < NCHUNK && tid != ch) {
            while (__hip_atomic_load(&flg[tid], __ATOMIC_RELAXED,
                                     __HIP_MEMORY_SCOPE_AGENT)
                   < FLAGBASE + (unsigned)(t + 1)) {}
        }
        __syncthreads();
        __builtin_amdgcn_fence(__ATOMIC_ACQUIRE, "agent");

        // copy 3 partner chunks (3 x 2 KB) into hn; own chunk already in LDS.
        // agent-scope loads (sc1): never served from a stale local cache.
        const unsigned short* hx = HxG + par * HBUF;
        #pragma unroll
        for (int uu = 0; uu < NCHUNK; ++uu) {
            if (uu != ch) {
                int u = uu * NTHREADS + tid;      // 8-byte unit index
                unsigned long long v = __hip_atomic_load(
                    (const unsigned long long*)(hx + u * 4),
                    __ATOMIC_RELAXED, __HIP_MEMORY_SCOPE_AGENT);
                ushortx4 hv;
                __builtin_memcpy(&hv, &v, 8);
                *(ushortx4*)(hn + u * 4) = hv;
            }
        }
        __syncthreads();
    }

    if (!IS_DEC) {
        // hand the decoder the EXACT fp32 final h (own 64 dims per block)
        *(f32x4*)(h_out + (size_t)(g * NBATCH + c) * HID + ht * 16 + q * 4) = hold;
    }
}

// out[b][t][d] = sum_h Y[g][t][b16][h] * W_fc[d][h] + b_fc[d]
__global__ __launch_bounds__(256) void proj_kernel(
    const unsigned short* __restrict__ Y, const float* __restrict__ W_fc,
    const float* __restrict__ b_fc, float* __restrict__ out)
{
    int row = blockIdx.x * 256 + threadIdx.x;  // ((g*T + t)*16 + b16)
    int b16 = row & 15;
    int gt = row >> 4;
    int t = gt & (T_LEN - 1);
    int g = gt >> 8;
    const unsigned short* y = Y + (size_t)row * HID;
    float a0 = b_fc[0], a1 = b_fc[1], a2 = b_fc[2];
    #pragma unroll 4
    for (int k8 = 0; k8 < 32; ++k8) {
        ushortx8 v = *(const ushortx8*)(y + k8 * 8);
        #pragma unroll
        for (int j = 0; j < 8; ++j) {
            float f = bf2f(v[j]);
            int k = k8 * 8 + j;
            a0 += f * W_fc[k];          // uniform -> scalar loads
            a1 += f * W_fc[256 + k];
            a2 += f * W_fc[512 + k];
        }
    }
    int batch = g * NBATCH + b16;
    float* o = out + ((size_t)batch * T_LEN + t) * 3;
    o[0] = a0; o[1] = a1; o[2] = a2;
}

extern "C" void kernel_launch(void* const* d_in, const int* in_sizes, int n_in,
                              void* d_out, int out_size, void* d_ws, size_t ws_size,
                              hipStream_t stream)
{
    const float* X_p      = (const float*)d_in[0];
    const float* X_f      = (const float*)d_in[1];
    const float* noise    = (const float*)d_in[2];
    const float* W_ih_enc = (const float*)d_in[3];
    const float* W_hh_enc = (const float*)d_in[4];
    const float* b_ih_enc = (const float*)d_in[5];
    const float* b_hh_enc = (const float*)d_in[6];
    const float* W_ih_dec = (const float*)d_in[7];
    const float* W_hh_dec = (const float*)d_in[8];
    const float* b_ih_dec = (const float*)d_in[9];
    const float* b_hh_dec = (const float*)d_in[10];
    const float* W_fc     = (const float*)d_in[11];
    const float* b_fc     = (const float*)d_in[12];

    // ws: [0,512K) h_enc fp32 | [512K,1024K) Hx exchange | [1024K,1028K) flags
    //     | [1028K, +67.1MB) decoder Y bf16
    float* h_enc = (float*)d_ws;
    unsigned short* Hx    = (unsigned short*)((char*)d_ws + (512u << 10));
    unsigned int*   flags = (unsigned int*)((char*)d_ws + (1024u << 10));
    unsigned short* Yws   = (unsigned short*)((char*)d_ws + (1028u << 10));

    // reset step flags each launch (graph-capture-safe memset node);
    // enc uses flag values 1..255, dec 257..511 (base +256), so one clear
    // per launch covers both kernels.
    (void)hipMemsetAsync(flags, 0, NGROUP * NCHUNK * sizeof(unsigned int), stream);

    // PLAIN launches: 128 blocks <= 256 CUs -> all co-resident; the flag
    // protocol needs co-residency only, not grid.sync().
    hipLaunchKernelGGL((gru_persistent<0>), dim3(NBLK), dim3(NTHREADS),
        SMEM_BYTES, stream,
        X_p, W_hh_enc, W_ih_enc, b_ih_enc, b_hh_enc,
        (const float*)nullptr, (const float*)nullptr, h_enc,
        (unsigned short*)nullptr, Hx, flags);

    hipLaunchKernelGGL((gru_persistent<1>), dim3(NBLK), dim3(NTHREADS),
        SMEM_BYTES, stream,
        X_f, W_hh_dec, W_ih_dec, b_ih_dec, b_hh_dec,
        h_enc, noise, (float*)nullptr, Yws, Hx, flags);

    hipLaunchKernelGGL(proj_kernel, dim3((B_TOT * T_LEN) / 256), dim3(256), 0, stream,
        Yws, W_fc, b_fc, (float*)d_out);
}

// Round 3
// 876.203 us; speedup vs baseline: 4.0591x; 4.0591x over previous
//
#include <hip/hip_runtime.h>

// NetG: seq2seq GRU (enc GRU -> +noise -> dec GRU -> FC head)
// B=512, T=256, H=256, D=3.
//
// R15 = R12 structure with NB=4 real batches per block, 128 blocks.
//   R14 post-mortem: per-step cross-block h exchange costs ~8us/step
//   (agent-scope RTT + fences) -> 2090us/GRU. Reverted to within-block
//   recurrence. New lever: the GRU chain is PER-BATCH independent, so
//   batch-group size is only an MFMA-N artifact. NB=4 real columns per
//   block (cols 4..15 padded) quarters the per-CU transcendental+VALU
//   epilogue while MFMA issue (~480 cyc/SIMD/step, the structural floor)
//   is N-independent. 128 blocks -> 128 CUs busy instead of 32.
//   Padding columns: x staged as 0 (bias-only garbage, tanh/sigmoid
//   bounded), h columns c>=NB never stored to Y/h_out; MFMA column c
//   only affects column c -> garbage fully contained.
// Frozen from R6..R12 (measured 413us/GRU at NB=16): 512 thr / 8 waves,
// 2 hidden tiles per wave; fp32 register h carry (exact); gates z,n
// resident in regs; gate r k=0..3 LDS frags / k=4..7 global L2 prefetch
// (prep_wr); fragment-order h in LDS double buffer, single barrier/step;
// native v_exp gates; x staged in LDS with decoder shift baked in;
// interleaved epilogue->x-step-MFMA tail.

#define B_TOT 512
#define T_LEN 256
#define HID 256
#define NBATCH 16              // MFMA column count (padded layout)
#define NB 4                   // real batches per block
#define NTHREADS 512
#define NBLK (B_TOT / NB)      // 128

// LDS partition (units: shorts)
#define WR_OFF 0               // gate-r k=0..3 frags: 16*4*64*8 = 32768
#define H_OFF  32768           // 2 x 4096
#define X_OFF  40960           // 257 x 64 = 16448
#define SMEM_SHORTS 57408
#define SMEM_BYTES  (SMEM_SHORTS * 2)   // 114816 B <= 160 KiB

#define XT 64
#define XSLOTS (T_LEN + 1)
#define HBUF (NBATCH * HID)

typedef __attribute__((ext_vector_type(4))) float f32x4;
typedef __attribute__((ext_vector_type(8))) short shortx8;
typedef __attribute__((ext_vector_type(4))) short i16x4;
typedef __attribute__((ext_vector_type(4))) unsigned short ushortx4;
typedef __attribute__((ext_vector_type(8))) unsigned short ushortx8;

#if __has_builtin(__builtin_amdgcn_mfma_f32_16x16x16_bf16)
#define HAVE_K16 1
#define MFMA_X(A, B, C) __builtin_amdgcn_mfma_f32_16x16x16_bf16((A), (B), (C), 0, 0, 0)
#elif __has_builtin(__builtin_amdgcn_mfma_f32_16x16x16bf16_1k)
#define HAVE_K16 1
#define MFMA_X(A, B, C) __builtin_amdgcn_mfma_f32_16x16x16bf16_1k((A), (B), (C), 0, 0, 0)
#else
#define HAVE_K16 0
#endif

__device__ __forceinline__ unsigned short f2bf(float x) {
    unsigned u = __float_as_uint(x);
    u += 0x7FFF + ((u >> 16) & 1);   // RNE
    return (unsigned short)(u >> 16);
}
__device__ __forceinline__ float bf2f(unsigned short s) {
    return __uint_as_float(((unsigned)s) << 16);
}
__device__ __forceinline__ float fastrcp(float x) {
#if __has_builtin(__builtin_amdgcn_rcpf)
    return __builtin_amdgcn_rcpf(x);
#else
    return 1.0f / x;
#endif
}
__device__ __forceinline__ float exp2raw(float y) {
#if __has_builtin(__builtin_amdgcn_exp2f)
    return __builtin_amdgcn_exp2f(y);
#else
    return __expf(y * 0.69314718056f);
#endif
}
__device__ __forceinline__ float sigmoid_(float x) {
    return fastrcp(1.0f + exp2raw(x * -1.44269504f));
}
__device__ __forceinline__ float tanh_(float x) {
    return 2.0f * fastrcp(1.0f + exp2raw(x * -2.88539008f)) - 1.0f;
}

// Pack gate-r (rows 0..255 of W_hh), K-half k=4..7, into per-lane fragment
// layout: dst[((ht*4+kk)*64+lane)*8+j] = bf16(W[ht*16+(lane&15)][(kk+4)*32+(lane>>4)*8+j])
__global__ __launch_bounds__(256) void prep_wr(
    const float* __restrict__ Whh_enc, const float* __restrict__ Whh_dec,
    unsigned short* __restrict__ wr_enc, unsigned short* __restrict__ wr_dec)
{
    int idx = blockIdx.x * 256 + threadIdx.x;    // 0..8191
    int gru = idx >> 12;
    int rem = idx & 4095;                        // (ht*4+kk)*64 + lane
    int lane = rem & 63;
    int kk = (rem >> 6) & 3;
    int ht = rem >> 8;
    const float* W = gru ? Whh_dec : Whh_enc;
    unsigned short* dst = gru ? wr_dec : wr_enc;
    int row = ht * 16 + (lane & 15);
    int col = (kk + 4) * 32 + (lane >> 4) * 8;
    const float* src = W + (size_t)row * 256 + col;
    ushortx8 v;
    #pragma unroll
    for (int j = 0; j < 8; ++j) v[j] = f2bf(src[j]);
    *(ushortx8*)(dst + (size_t)rem * 8) = v;
}

template<int IS_DEC>
__global__ __launch_bounds__(NTHREADS, 2) void gru_persistent(
    const float* __restrict__ X,       // [512][256][3]
    const float* __restrict__ W_hh,    // [768][256] gates r,z,n
    const float* __restrict__ W_ih,    // [768][3]
    const float* __restrict__ b_ih,    // [768]
    const float* __restrict__ b_hh,    // [768]
    const unsigned short* __restrict__ Wr4, // gate-r k=4..7 frags (prep_wr)
    const float* __restrict__ h_in,    // dec: [512][256] fp32; enc: null
    const float* __restrict__ noise,   // dec: [512][256]; enc: null
    float* __restrict__ h_out,         // enc: [512][256] fp32; dec: null
    unsigned short* __restrict__ Yout) // dec: [128][256][4][256] bf16
{
    extern __shared__ unsigned short smem[];
    unsigned short* shWr = smem + WR_OFF;
    unsigned short* shH  = smem + H_OFF;
    unsigned short* shX  = smem + X_OFF;

    const int tid  = threadIdx.x;
    const int g    = blockIdx.x;      // batch-group of NB
    const int w    = tid >> 6;        // wave; owns hidden tiles {w, w+8}
    const int lane = tid & 63;
    const int c    = lane & 15;       // MFMA column (batch slot)
    const int q    = lane >> 4;

    // ---- stage X into LDS (bf16, shift baked in; slot t = x for step t) ----
    // cols cc >= NB stay zero (pad 1.0 in slot 3 keeps bias path uniform;
    // resulting pad-column h is bounded garbage, never read).
    for (int idx = tid; idx < NBATCH * XSLOTS; idx += NTHREADS) {
        int t = idx >> 4, cc = idx & 15;
        int ts = IS_DEC ? (t - 1) : t;
        float x0 = 0.0f, x1 = 0.0f, x2 = 0.0f;
        if (cc < NB && ts >= 0 && ts < T_LEN) {
            const float* xp = X + ((size_t)(g * NB + cc) * T_LEN + ts) * 3;
            x0 = xp[0]; x1 = xp[1]; x2 = xp[2];
        }
        ushortx4 v = {f2bf(x0), f2bf(x1), f2bf(x2), (unsigned short)0x3F80};
        *(ushortx4*)&shX[t * XT + cc * 4] = v;
    }

    // ---- gate-r k=0..3 frags -> LDS (each wave stages its 2 tiles) ----
    #pragma unroll
    for (int hti = 0; hti < 2; ++hti) {
        int ht = w + hti * 8;
        int row = ht * 16 + c;                      // gate r
        const float* wp = W_hh + (size_t)row * 256 + q * 8;
        #pragma unroll
        for (int k = 0; k < 4; ++k) {
            const f32x4* p = (const f32x4*)(wp + k * 32);
            f32x4 f0 = p[0];
            f32x4 f1 = p[1];
            shortx8 a;
            a[0] = (short)f2bf(f0[0]); a[1] = (short)f2bf(f0[1]);
            a[2] = (short)f2bf(f0[2]); a[3] = (short)f2bf(f0[3]);
            a[4] = (short)f2bf(f1[0]); a[5] = (short)f2bf(f1[1]);
            a[6] = (short)f2bf(f1[2]); a[7] = (short)f2bf(f1[3]);
            *(shortx8*)&shWr[((ht * 4 + k) * 64 + lane) * 8] = a;
        }
    }

    // ---- gates z,n A-frags into registers (128 regs, resident) ----
    shortx8 Wf[2][2][8];   // [hti][z|n][k]
    #pragma unroll
    for (int hti = 0; hti < 2; ++hti) {
        int ht = w + hti * 8;
        #pragma unroll
        for (int gg = 0; gg < 2; ++gg) {
            int row = (gg + 1) * 256 + ht * 16 + c;
            const float* wp = W_hh + (size_t)row * 256 + q * 8;
            #pragma unroll
            for (int k = 0; k < 8; ++k) {
                const f32x4* p = (const f32x4*)(wp + k * 32);
                f32x4 f0 = p[0];
                f32x4 f1 = p[1];
                shortx8 a;
                a[0] = (short)f2bf(f0[0]); a[1] = (short)f2bf(f0[1]);
                a[2] = (short)f2bf(f0[2]); a[3] = (short)f2bf(f0[3]);
                a[4] = (short)f2bf(f1[0]); a[5] = (short)f2bf(f1[1]);
                a[6] = (short)f2bf(f1[2]); a[7] = (short)f2bf(f1[3]);
                Wf[hti][gg][k] = a;
            }
        }
    }

    // ---- x/bias A-frags (q==0 lanes carry data; others MUST be zero) ----
#if HAVE_K16
    i16x4 ax[2][3];
#else
    shortx8 ax[2][3];
#endif
    #pragma unroll
    for (int hti = 0; hti < 2; ++hti) {
        int ht = w + hti * 8;
        int rr = ht * 16 + c;
        int rowr = rr, rowz = 256 + rr, rown = 512 + rr;
        short r0 = 0, r1 = 0, r2 = 0, r3 = 0, z0 = 0, z1 = 0, z2 = 0, z3 = 0;
        short n0 = 0, n1 = 0, n2 = 0, n3 = 0;
        if (q == 0) {
            r0 = (short)f2bf(W_ih[rowr * 3 + 0]);
            r1 = (short)f2bf(W_ih[rowr * 3 + 1]);
            r2 = (short)f2bf(W_ih[rowr * 3 + 2]);
            r3 = (short)f2bf(b_ih[rowr] + b_hh[rowr]);
            z0 = (short)f2bf(W_ih[rowz * 3 + 0]);
            z1 = (short)f2bf(W_ih[rowz * 3 + 1]);
            z2 = (short)f2bf(W_ih[rowz * 3 + 2]);
            z3 = (short)f2bf(b_ih[rowz] + b_hh[rowz]);
            n0 = (short)f2bf(W_ih[rown * 3 + 0]);
            n1 = (short)f2bf(W_ih[rown * 3 + 1]);
            n2 = (short)f2bf(W_ih[rown * 3 + 2]);
            n3 = (short)f2bf(b_ih[rown]);
        }
#if HAVE_K16
        ax[hti][0] = i16x4{r0, r1, r2, r3};
        ax[hti][1] = i16x4{z0, z1, z2, z3};
        ax[hti][2] = i16x4{n0, n1, n2, n3};
#else
        ax[hti][0] = shortx8{r0, r1, r2, r3, 0, 0, 0, 0};
        ax[hti][1] = shortx8{z0, z1, z2, z3, 0, 0, 0, 0};
        ax[hti][2] = shortx8{n0, n1, n2, n3, 0, 0, 0, 0};
#endif
    }

    // ---- nh-bias register constants (b_hh n-gate, this lane's D rows) ----
    f32x4 nhb[2];
    #pragma unroll
    for (int hti = 0; hti < 2; ++hti) {
        int ht = w + hti * 8;
        nhb[hti] = *(const f32x4*)(b_hh + 512 + ht * 16 + q * 4);
    }

    // ---- epilogue offsets (fragment-order), loop-invariant ----
    int woff[2];
    #pragma unroll
    for (int hti = 0; hti < 2; ++hti) {
        int ht = w + hti * 8;
        int kk = ht >> 1;
        int qq = ((ht & 1) << 1) | (q >> 1);
        woff[hti] = ((kk * 4 + qq) * 16 + c) * 8 + (q & 1) * 4;
    }

    // ---- init h0: fp32 carry in regs; bf16 copy into buffer 0 ----
    const bool real_col = (c < NB);
    f32x4 hold[2];
    #pragma unroll
    for (int hti = 0; hti < 2; ++hti) {
        int ht = w + hti * 8;
        int dim0 = ht * 16 + q * 4;
        f32x4 hv = {0.0f, 0.0f, 0.0f, 0.0f};
        if (IS_DEC && real_col) {
            int b = g * NB + c;
            f32x4 h0 = *(const f32x4*)(h_in + (size_t)b * HID + dim0);
            f32x4 nz = *(const f32x4*)(noise + (size_t)b * HID + dim0);
            hv = h0 + nz;
        }
        hold[hti] = hv;
        ushortx4 hb16 = {f2bf(hv[0]), f2bf(hv[1]), f2bf(hv[2]), f2bf(hv[3])};
        *(ushortx4*)&shH[woff[hti]] = hb16;
    }

    // ---- incremental decoder Y pointers (step stride = NB*HID shorts) ----
    unsigned short* yp[2];
    #pragma unroll
    for (int hti = 0; hti < 2; ++hti) {
        int ht = w + hti * 8;
        yp[hti] = Yout + ((size_t)g * T_LEN * NB + c) * HID + ht * 16 + q * 4;
    }
    __syncthreads();

    const f32x4 zc = {0.0f, 0.0f, 0.0f, 0.0f};

    // ---- x-step for t=0 (C = inline 0 initializes acc r/z/nx) ----
    f32x4 acc[2][4];  // [hti][r, z, nh, nx]
    {
#if HAVE_K16
        i16x4 bx = *(const i16x4*)&shX[c * 4];
        #pragma unroll
        for (int hti = 0; hti < 2; ++hti) {
            acc[hti][0] = MFMA_X(ax[hti][0], bx, zc);
            acc[hti][1] = MFMA_X(ax[hti][1], bx, zc);
            acc[hti][3] = MFMA_X(ax[hti][2], bx, zc);
        }
#else
        ushortx4 xv = *(const ushortx4*)&shX[c * 4];
        shortx8 bx = (q == 0)
            ? shortx8{(short)xv[0], (short)xv[1], (short)xv[2], (short)xv[3], 0, 0, 0, 0}
            : shortx8{0, 0, 0, 0, 0, 0, 0, 0};
        #pragma unroll
        for (int hti = 0; hti < 2; ++hti) {
            acc[hti][0] = __builtin_amdgcn_mfma_f32_16x16x32_bf16(ax[hti][0], bx, zc, 0, 0, 0);
            acc[hti][1] = __builtin_amdgcn_mfma_f32_16x16x32_bf16(ax[hti][1], bx, zc, 0, 0, 0);
            acc[hti][3] = __builtin_amdgcn_mfma_f32_16x16x32_bf16(ax[hti][2], bx, zc, 0, 0, 0);
        }
#endif
    }

    const int bbase = q * 128 + c * 8;   // lane's B-frag base within a buffer
    const unsigned short* ab0 = shWr + ((size_t)(w * 4) * 64 + lane) * 8;
    const unsigned short* ab1 = shWr + ((size_t)((w + 8) * 4) * 64 + lane) * 8;
    const unsigned short* gb0 = Wr4 + ((size_t)(w * 4) * 64 + lane) * 8;
    const unsigned short* gb1 = Wr4 + ((size_t)((w + 8) * 4) * 64 + lane) * 8;

    int xidx = XT + c * 4;   // x slot for step t+1 (incremental)

    // ---- recurrence ----
    for (int t = 0; t < T_LEN; ++t) {
        const unsigned short* hb = shH + (t & 1) * HBUF;
        unsigned short* hn = shH + ((t + 1) & 1) * HBUF;
        const unsigned short* brow = hb + bbase;

        // gate-r k=4..7 from global: issued at step start, consumed after
        // the LDS half (~460 cyc of MFMA slack — R6's proven timing)
        shortx8 gr0[4], gr1[4];
        #pragma unroll
        for (int kk = 0; kk < 4; ++kk) {
            gr0[kk] = *(const shortx8*)(gb0 + kk * 512);
            gr1[kk] = *(const shortx8*)(gb1 + kk * 512);
        }

        // n-gate hidden accumulators start from the b_hh bias constants
        acc[0][2] = nhb[0];
        acc[1][2] = nhb[1];

        // k=0..3: gate-r from LDS
        #pragma unroll
        for (int k = 0; k < 4; ++k) {
            shortx8 bf  = *(const shortx8*)(brow + k * 512);
            shortx8 ar0 = *(const shortx8*)(ab0 + k * 512);
            shortx8 ar1 = *(const shortx8*)(ab1 + k * 512);
            acc[0][0] = __builtin_amdgcn_mfma_f32_16x16x32_bf16(ar0,         bf, acc[0][0], 0, 0, 0);
            acc[1][0] = __builtin_amdgcn_mfma_f32_16x16x32_bf16(ar1,         bf, acc[1][0], 0, 0, 0);
            acc[0][1] = __builtin_amdgcn_mfma_f32_16x16x32_bf16(Wf[0][0][k], bf, acc[0][1], 0, 0, 0);
            acc[1][1] = __builtin_amdgcn_mfma_f32_16x16x32_bf16(Wf[1][0][k], bf, acc[1][1], 0, 0, 0);
            acc[0][2] = __builtin_amdgcn_mfma_f32_16x16x32_bf16(Wf[0][1][k], bf, acc[0][2], 0, 0, 0);
            acc[1][2] = __builtin_amdgcn_mfma_f32_16x16x32_bf16(Wf[1][1][k], bf, acc[1][2], 0, 0, 0);
        }
        // k=4..7: gate-r from the global prefetch
        #pragma unroll
        for (int k = 4; k < 8; ++k) {
            shortx8 bf = *(const shortx8*)(brow + k * 512);
            acc[0][0] = __builtin_amdgcn_mfma_f32_16x16x32_bf16(gr0[k - 4],  bf, acc[0][0], 0, 0, 0);
            acc[1][0] = __builtin_amdgcn_mfma_f32_16x16x32_bf16(gr1[k - 4],  bf, acc[1][0], 0, 0, 0);
            acc[0][1] = __builtin_amdgcn_mfma_f32_16x16x32_bf16(Wf[0][0][k], bf, acc[0][1], 0, 0, 0);
            acc[1][1] = __builtin_amdgcn_mfma_f32_16x16x32_bf16(Wf[1][0][k], bf, acc[1][1], 0, 0, 0);
            acc[0][2] = __builtin_amdgcn_mfma_f32_16x16x32_bf16(Wf[0][1][k], bf, acc[0][2], 0, 0, 0);
            acc[1][2] = __builtin_amdgcn_mfma_f32_16x16x32_bf16(Wf[1][1][k], bf, acc[1][2], 0, 0, 0);
        }

        // bx for step t+1 (read once; used per tile right after its epilogue)
#if HAVE_K16
        i16x4 bxn = *(const i16x4*)&shX[xidx];
#else
        ushortx4 xvn = *(const ushortx4*)&shX[xidx];
        shortx8 bxn = (q == 0)
            ? shortx8{(short)xvn[0], (short)xvn[1], (short)xvn[2], (short)xvn[3], 0, 0, 0, 0}
            : shortx8{0, 0, 0, 0, 0, 0, 0, 0};
#endif
        xidx += XT;

        // ---- interleaved tail: epilogue(tile) then its x-step re-init ----
        #pragma unroll
        for (int hti = 0; hti < 2; ++hti) {
            f32x4 hv = hold[hti];
            f32x4 ho;
            #pragma unroll
            for (int r = 0; r < 4; ++r) {
                float rr = sigmoid_(acc[hti][0][r]);
                float zz = sigmoid_(acc[hti][1][r]);
                float nn = tanh_(acc[hti][3][r] + rr * acc[hti][2][r]);
                ho[r] = nn + zz * (hv[r] - nn);
            }
            hold[hti] = ho;
            ushortx4 hb16 = {f2bf(ho[0]), f2bf(ho[1]), f2bf(ho[2]), f2bf(ho[3])};
            *(ushortx4*)(hn + woff[hti]) = hb16;
            if (IS_DEC && real_col) {
                *(ushortx4*)yp[hti] = hb16;
            }
            if (IS_DEC) yp[hti] += NB * HID;   // stride NB*256 shorts per step
            // x-step re-init for t+1 (independent MFMAs under the trans tail)
#if HAVE_K16
            acc[hti][0] = MFMA_X(ax[hti][0], bxn, zc);
            acc[hti][1] = MFMA_X(ax[hti][1], bxn, zc);
            acc[hti][3] = MFMA_X(ax[hti][2], bxn, zc);
#else
            acc[hti][0] = __builtin_amdgcn_mfma_f32_16x16x32_bf16(ax[hti][0], bxn, zc, 0, 0, 0);
            acc[hti][1] = __builtin_amdgcn_mfma_f32_16x16x32_bf16(ax[hti][1], bxn, zc, 0, 0, 0);
            acc[hti][3] = __builtin_amdgcn_mfma_f32_16x16x32_bf16(ax[hti][2], bxn, zc, 0, 0, 0);
#endif
        }
        __syncthreads();
    }

    if (!IS_DEC && real_col) {
        // hand the decoder the EXACT fp32 final h (4 real batches/block)
        #pragma unroll
        for (int hti = 0; hti < 2; ++hti) {
            int ht = w + hti * 8;
            int dim0 = ht * 16 + q * 4;
            *(f32x4*)(h_out + (size_t)(g * NB + c) * HID + dim0) = hold[hti];
        }
    }
}

// out[b][t][d] = sum_h Y[g][t][b4][h] * W_fc[d][h] + b_fc[d]
// Y layout: [128][256][4][256]
__global__ __launch_bounds__(256) void proj_kernel(
    const unsigned short* __restrict__ Y, const float* __restrict__ W_fc,
    const float* __restrict__ b_fc, float* __restrict__ out)
{
    int row = blockIdx.x * 256 + threadIdx.x;  // ((g*T + t)*NB + b4)
    int b4 = row & (NB - 1);
    int gt = row >> 2;                         // g*T + t
    int t = gt & (T_LEN - 1);
    int g = gt >> 8;
    const unsigned short* y = Y + (size_t)row * HID;
    float a0 = b_fc[0], a1 = b_fc[1], a2 = b_fc[2];
    #pragma unroll 4
    for (int k8 = 0; k8 < 32; ++k8) {
        ushortx8 v = *(const ushortx8*)(y + k8 * 8);
        #pragma unroll
        for (int j = 0; j < 8; ++j) {
            float f = bf2f(v[j]);
            int k = k8 * 8 + j;
            a0 += f * W_fc[k];          // uniform -> scalar loads
            a1 += f * W_fc[256 + k];
            a2 += f * W_fc[512 + k];
        }
    }
    int batch = g * NB + b4;
    float* o = out + ((size_t)batch * T_LEN + t) * 3;
    o[0] = a0; o[1] = a1; o[2] = a2;
}

extern "C" void kernel_launch(void* const* d_in, const int* in_sizes, int n_in,
                              void* d_out, int out_size, void* d_ws, size_t ws_size,
                              hipStream_t stream)
{
    const float* X_p      = (const float*)d_in[0];
    const float* X_f      = (const float*)d_in[1];
    const float* noise    = (const float*)d_in[2];
    const float* W_ih_enc = (const float*)d_in[3];
    const float* W_hh_enc = (const float*)d_in[4];
    const float* b_ih_enc = (const float*)d_in[5];
    const float* b_hh_enc = (const float*)d_in[6];
    const float* W_ih_dec = (const float*)d_in[7];
    const float* W_hh_dec = (const float*)d_in[8];
    const float* b_ih_dec = (const float*)d_in[9];
    const float* b_hh_dec = (const float*)d_in[10];
    const float* W_fc     = (const float*)d_in[11];
    const float* b_fc     = (const float*)d_in[12];

    // allow >64 KiB dynamic LDS (idempotent; host-side, graph-capture safe)
    (void)hipFuncSetAttribute((const void*)&gru_persistent<0>,
                              hipFuncAttributeMaxDynamicSharedMemorySize, SMEM_BYTES);
    (void)hipFuncSetAttribute((const void*)&gru_persistent<1>,
                              hipFuncAttributeMaxDynamicSharedMemorySize, SMEM_BYTES);

    // ws: [0,512K) h_enc fp32 | [512K,576K) Wr_enc | [576K,640K) Wr_dec |
    //     [640K, +67.1MB) decoder Y bf16
    float* h_enc = (float*)d_ws;
    unsigned short* wr_enc = (unsigned short*)((char*)d_ws + (512u << 10));
    unsigned short* wr_dec = (unsigned short*)((char*)d_ws + (576u << 10));
    unsigned short* Yws    = (unsigned short*)((char*)d_ws + (640u << 10));

    hipLaunchKernelGGL(prep_wr, dim3(32), dim3(256), 0, stream,
        W_hh_enc, W_hh_dec, wr_enc, wr_dec);

    hipLaunchKernelGGL((gru_persistent<0>), dim3(NBLK), dim3(NTHREADS), SMEM_BYTES, stream,
        X_p, W_hh_enc, W_ih_enc, b_ih_enc, b_hh_enc, wr_enc,
        (const float*)nullptr, (const float*)nullptr, h_enc,
        (unsigned short*)nullptr);

    hipLaunchKernelGGL((gru_persistent<1>), dim3(NBLK), dim3(NTHREADS), SMEM_BYTES, stream,
        X_f, W_hh_dec, W_ih_dec, b_ih_dec, b_hh_dec, wr_dec,
        h_enc, noise, (float*)nullptr, Yws);

    hipLaunchKernelGGL(proj_kernel, dim3((B_TOT * T_LEN) / 256), dim3(256), 0, stream,
        Yws, W_fc, b_fc, (float*)d_out);
}